// Round 1
// baseline (151.881 us; speedup 1.0000x reference)
//
#include <hip/hip_runtime.h>

#define KK 27

typedef short bf16x8 __attribute__((ext_vector_type(8)));   // 8 bf16 in 4 VGPRs
typedef float f32x4  __attribute__((ext_vector_type(4)));

__device__ inline unsigned short f2bf(float f) {            // RNE fp32 -> bf16
    unsigned u = __float_as_uint(f);
    unsigned r = u + 0x7fffu + ((u >> 16) & 1u);
    return (unsigned short)(r >> 16);
}

// ---- Kernel 1 (fused prep): blocks [0,nxblk) transpose+cast x; blocks [nxblk, nxblk+27) prep W ----
// x [32][N] fp32 -> xTb [N+1][32] bf16 (row N is an all-zero row used by out-of-range lanes)
// weight [27][cin=32][cout=32] fp32 -> wTb [27][cout=32][cin=32] bf16
__global__ __launch_bounds__(256) void prep_k(const float* __restrict__ in,
                                              const float* __restrict__ w,
                                              unsigned short* __restrict__ xTb,
                                              unsigned short* __restrict__ wTb,
                                              int N, int nxblk) {
    __shared__ float tile[32][33];
    const int b = blockIdx.x;
    if (b < nxblk) {
        int n0 = b * 32;
        int tx = threadIdx.x & 31;
        int ty = threadIdx.x >> 5;  // 0..7
#pragma unroll
        for (int c = ty; c < 32; c += 8) {
            int n = n0 + tx;
            tile[c][tx] = (n < N) ? in[(long)c * N + n] : 0.f;
        }
        __syncthreads();
#pragma unroll
        for (int nn = ty; nn < 32; nn += 8) {
            int n = n0 + nn;
            if (n < N) xTb[(long)n * 32 + tx] = f2bf(tile[tx][nn]);
        }
        if (b == 0 && threadIdx.x < 32) xTb[(long)N * 32 + threadIdx.x] = 0;  // zero row
    } else {
        int k = b - nxblk;
        for (int i = threadIdx.x; i < 1024; i += 256) {
            int cin = i >> 5, cout = i & 31;
            wTb[k * 1024 + cout * 32 + cin] = f2bf(w[k * 1024 + cin * 32 + cout]);
        }
    }
}

// ---- pipelined tap loop: depth-3 data prefetch, indices prefetched 6 taps ahead ----
// Invalid lanes (node >= N) get index N -> gather the zero row (no per-element cndmask).
template <int CNT>
__device__ __forceinline__ void conv_taps(int k0,
                                          const unsigned short* __restrict__ xTb,
                                          const int* __restrict__ neigh,
                                          const unsigned short* __restrict__ wTb,
                                          long nb0, long nb1, bool v0, bool v1,
                                          int r16, int quad, int N,
                                          f32x4& acc00, f32x4& acc01,
                                          f32x4& acc10, f32x4& acc11) {
    bf16x8 A0[3], A1[3], B0[3], B1[3];
    int ja[3], jb[3];

#pragma unroll
    for (int d = 0; d < 3; ++d) {
        int kk = k0 + (d < CNT ? d : CNT - 1);
        ja[d] = v0 ? neigh[nb0 + kk] : N;
        jb[d] = v1 ? neigh[nb1 + kk] : N;
    }
#pragma unroll
    for (int d = 0; d < 3; ++d) {
        int kk = k0 + (d < CNT ? d : CNT - 1);
        A0[d] = *(const bf16x8*)(xTb + (long)ja[d] * 32 + quad * 8);
        A1[d] = *(const bf16x8*)(xTb + (long)jb[d] * 32 + quad * 8);
        const unsigned short* wn = wTb + kk * 1024;
        B0[d] = *(const bf16x8*)(wn + r16 * 32 + quad * 8);
        B1[d] = *(const bf16x8*)(wn + (16 + r16) * 32 + quad * 8);
        int k2 = k0 + (d + 3 < CNT ? d + 3 : CNT - 1);
        ja[d] = v0 ? neigh[nb0 + k2] : N;
        jb[d] = v1 ? neigh[nb1 + k2] : N;
    }
#pragma unroll
    for (int t = 0; t < CNT; ++t) {
        const int cur = t % 3;   // compile-time (full unroll)
        acc00 = __builtin_amdgcn_mfma_f32_16x16x32_bf16(A0[cur], B0[cur], acc00, 0, 0, 0);
        acc01 = __builtin_amdgcn_mfma_f32_16x16x32_bf16(A0[cur], B1[cur], acc01, 0, 0, 0);
        acc10 = __builtin_amdgcn_mfma_f32_16x16x32_bf16(A1[cur], B0[cur], acc10, 0, 0, 0);
        acc11 = __builtin_amdgcn_mfma_f32_16x16x32_bf16(A1[cur], B1[cur], acc11, 0, 0, 0);
        if (t + 3 < CNT) {
            const int kk = k0 + t + 3;
            A0[cur] = *(const bf16x8*)(xTb + (long)ja[cur] * 32 + quad * 8);
            A1[cur] = *(const bf16x8*)(xTb + (long)jb[cur] * 32 + quad * 8);
            const unsigned short* wn = wTb + kk * 1024;
            B0[cur] = *(const bf16x8*)(wn + r16 * 32 + quad * 8);
            B1[cur] = *(const bf16x8*)(wn + (16 + r16) * 32 + quad * 8);
            const int k2 = k0 + (t + 6 < CNT ? t + 6 : CNT - 1);
            ja[cur] = v0 ? neigh[nb0 + k2] : N;
            jb[cur] = v1 ? neigh[nb1 + k2] : N;
        }
    }
}

// ---- Kernel 2: MFMA conv + BN partial atomics ----
// 256 threads = 4 waves per block; block covers 64 nodes.
// wave w: node-group gi = w>>1 (32 nodes), tap-half khalf = w&1 (taps 0..13 / 14..26).
// K-split doubles wave concurrency; LDS combine merges the two tap-halves.
__global__ __launch_bounds__(256, 4) void conv_k(const unsigned short* __restrict__ xTb,
                                                 const int* __restrict__ neigh,
                                                 const unsigned short* __restrict__ wTb,
                                                 float* __restrict__ y,    // [32][N]
                                                 float* __restrict__ tot,  // [64] atomic
                                                 int N) {
    __shared__ float cmb[2][16][64];   // K-split combine: [group][reg][lane]
    __shared__ float ct[2][32][33];    // transpose for coalesced y stores
    __shared__ float pr[4][16];        // BN partial handoff (wave2 -> wave0)

    const int tid   = threadIdx.x;
    const int L     = tid & 63;
    const int w     = tid >> 6;   // 0..3
    const int gi    = w >> 1;     // node group in block
    const int khalf = w & 1;      // tap half
    const int r16   = L & 15;
    const int quad  = L >> 4;
    const int base  = blockIdx.x * 64 + gi * 32;
    const int n0 = base + r16;
    const int n1 = base + 16 + r16;
    const bool v0 = (n0 < N), v1 = (n1 < N);
    const long nb0 = (long)(v0 ? n0 : 0) * KK;
    const long nb1 = (long)(v1 ? n1 : 0) * KK;

    f32x4 acc00 = {0.f, 0.f, 0.f, 0.f};
    f32x4 acc01 = acc00, acc10 = acc00, acc11 = acc00;

    if (khalf == 0)
        conv_taps<14>(0,  xTb, neigh, wTb, nb0, nb1, v0, v1, r16, quad, N,
                      acc00, acc01, acc10, acc11);
    else
        conv_taps<13>(14, xTb, neigh, wTb, nb0, nb1, v0, v1, r16, quad, N,
                      acc00, acc01, acc10, acc11);

    if (khalf == 1) {
#pragma unroll
        for (int r = 0; r < 4; ++r) {
            cmb[gi][r][L]      = acc00[r];
            cmb[gi][4 + r][L]  = acc01[r];
            cmb[gi][8 + r][L]  = acc10[r];
            cmb[gi][12 + r][L] = acc11[r];
        }
    }
    __syncthreads();

    float s0 = 0.f, q0 = 0.f, s1 = 0.f, q1 = 0.f;
    if (khalf == 0) {
#pragma unroll
        for (int r = 0; r < 4; ++r) {
            acc00[r] += cmb[gi][r][L];
            acc01[r] += cmb[gi][4 + r][L];
            acc10[r] += cmb[gi][8 + r][L];
            acc11[r] += cmb[gi][12 + r][L];
        }

        // BN partials: sum over this wave's 32 nodes.
#pragma unroll
        for (int r = 0; r < 4; ++r) {
            s0 += acc00[r] + acc10[r];
            q0 += acc00[r] * acc00[r] + acc10[r] * acc10[r];
            s1 += acc01[r] + acc11[r];
            q1 += acc01[r] * acc01[r] + acc11[r] * acc11[r];
        }
#pragma unroll
        for (int off = 16; off < 64; off <<= 1) {
            s0 += __shfl_xor(s0, off, 64);
            q0 += __shfl_xor(q0, off, 64);
            s1 += __shfl_xor(s1, off, 64);
            q1 += __shfl_xor(q1, off, 64);
        }
        if (w == 2 && L < 16) {
            pr[0][L] = s0; pr[1][L] = s1; pr[2][L] = q0; pr[3][L] = q1;
        }

        // stage transpose: ct[gi][node_in_group][cout]
#pragma unroll
        for (int r = 0; r < 4; ++r) {
            ct[gi][quad * 4 + r][r16]           = acc00[r];
            ct[gi][quad * 4 + r][16 + r16]      = acc01[r];
            ct[gi][16 + quad * 4 + r][r16]      = acc10[r];
            ct[gi][16 + quad * 4 + r][16 + r16] = acc11[r];
        }
    }
    __syncthreads();

    // one set of 64 atomics per block: wave 0 merges wave 2's partials
    if (w == 0 && L < 16) {
        atomicAdd(&tot[L],      s0 + pr[0][L]);
        atomicAdd(&tot[L + 16], s1 + pr[1][L]);
        atomicAdd(&tot[L + 32], q0 + pr[2][L]);
        atomicAdd(&tot[L + 48], q1 + pr[3][L]);
    }

    // coalesced y stores: each wave stores 8 couts x 64 contiguous nodes
    const int node = tid & 63;
    const int gn = blockIdx.x * 64 + node;
    if (gn < N) {
#pragma unroll
        for (int i = 0; i < 8; ++i) {
            const int cout = (tid >> 6) * 8 + i;
            y[(long)cout * N + gn] = ct[node >> 5][node & 31][cout];
        }
    }
}

// ---- Kernel 3: normalize y in place (stats finalize fused) ----
__global__ __launch_bounds__(256) void norm_k(float* __restrict__ y,
                                              const float* __restrict__ tot,
                                              const float* __restrict__ gamma,
                                              const float* __restrict__ beta, int N) {
    const int d = blockIdx.y;
    const float mean = tot[d] / (float)N;
    const float var  = tot[d + 32] / (float)N - mean * mean;
    const float sc   = gamma[d] * rsqrtf(var + 1e-3f);
    const float sh   = beta[d] - mean * sc;

    int i = blockIdx.x * blockDim.x + threadIdx.x;
    int base = i * 4;
    if (base + 3 < N) {
        float4* p = (float4*)(y + (long)d * N + base);
        float4 v = *p;
        v.x = fmaf(v.x, sc, sh);
        v.y = fmaf(v.y, sc, sh);
        v.z = fmaf(v.z, sc, sh);
        v.w = fmaf(v.w, sc, sh);
        *p = v;
    } else if (base < N) {
        for (int t = base; t < N; ++t) y[(long)d * N + t] = fmaf(y[(long)d * N + t], sc, sh);
    }
}

// ---- launcher ----
extern "C" void kernel_launch(void* const* d_in, const int* in_sizes, int n_in,
                              void* d_out, int out_size, void* d_ws, size_t ws_size,
                              hipStream_t stream) {
    const float* data_in = (const float*)d_in[0];
    const int*   neigh   = (const int*)d_in[1];
    const float* weight  = (const float*)d_in[2];
    const float* gamma   = (const float*)d_in[3];
    const float* beta    = (const float*)d_in[4];
    float* out = (float*)d_out;

    const int N = in_sizes[1] / KK;
    const int nxblk  = (N + 31) / 32;
    const int nblk64 = (N + 63) / 64;

    char* ws = (char*)d_ws;
    unsigned short* xTb = (unsigned short*)ws;                            // (N+1)*32 bf16
    unsigned short* wTb = (unsigned short*)(ws + (size_t)(N + 1) * 64);   // 27*1024 bf16
    float* tot = (float*)(ws + (size_t)(N + 1) * 64 + 55296);             // 64 floats

    hipMemsetAsync(tot, 0, 64 * sizeof(float), stream);
    prep_k<<<nxblk + KK, 256, 0, stream>>>(data_in, weight, xTb, wTb, N, nxblk);
    conv_k<<<nblk64, 256, 0, stream>>>(xTb, neigh, wTb, out, tot, N);
    dim3 ngrid(((N + 3) / 4 + 255) / 256, 32);
    norm_k<<<ngrid, 256, 0, stream>>>(out, tot, gamma, beta, N);
}

// Round 2
// 135.550 us; speedup vs baseline: 1.1205x; 1.1205x over previous
//
#include <hip/hip_runtime.h>

#define KK 27

typedef short bf16x8 __attribute__((ext_vector_type(8)));   // 8 bf16 in 4 VGPRs
typedef float f32x4  __attribute__((ext_vector_type(4)));

__device__ inline unsigned short f2bf(float f) {            // RNE fp32 -> bf16
    unsigned u = __float_as_uint(f);
    unsigned r = u + 0x7fffu + ((u >> 16) & 1u);
    return (unsigned short)(r >> 16);
}

// ---- Kernel 1 (fused prep): blocks [0,nxblk) transpose+cast x; blocks [nxblk, nxblk+27) prep W ----
// x [32][N] fp32 -> xTb [N+1][32] bf16 (row N is an all-zero row used by out-of-range lanes)
// weight [27][cin=32][cout=32] fp32 -> wTb [27][cout=32][cin=32] bf16
// block nxblk (k==0) additionally zeroes the striped BN accumulator tot[32*64]
// (safe: conv_k launches after prep_k completes, stream-ordered).
__global__ __launch_bounds__(256) void prep_k(const float* __restrict__ in,
                                              const float* __restrict__ w,
                                              unsigned short* __restrict__ xTb,
                                              unsigned short* __restrict__ wTb,
                                              float* __restrict__ tot,
                                              int N, int nxblk) {
    __shared__ float tile[32][33];
    const int b = blockIdx.x;
    if (b < nxblk) {
        int n0 = b * 32;
        int tx = threadIdx.x & 31;
        int ty = threadIdx.x >> 5;  // 0..7
#pragma unroll
        for (int c = ty; c < 32; c += 8) {
            int n = n0 + tx;
            tile[c][tx] = (n < N) ? in[(long)c * N + n] : 0.f;
        }
        __syncthreads();
#pragma unroll
        for (int nn = ty; nn < 32; nn += 8) {
            int n = n0 + nn;
            if (n < N) xTb[(long)n * 32 + tx] = f2bf(tile[tx][nn]);
        }
        if (b == 0 && threadIdx.x < 32) xTb[(long)N * 32 + threadIdx.x] = 0;  // zero row
    } else {
        int k = b - nxblk;
        for (int i = threadIdx.x; i < 1024; i += 256) {
            int cin = i >> 5, cout = i & 31;
            wTb[k * 1024 + cout * 32 + cin] = f2bf(w[k * 1024 + cin * 32 + cout]);
        }
        if (k == 0) {
            for (int i = threadIdx.x; i < 32 * 64; i += 256) tot[i] = 0.f;
        }
    }
}

// ---- Kernel 2: MFMA conv + BN striped atomics ----
// ONE wave per 16 nodes (no barriers, no K-split): 6250 independent waves for N=100k.
// Per tap: 1 A-gather (16 random 64B lines) + 2 B loads (L2-hot) + 2 MFMA.
// Depth-3 software pipeline, FULLY UNROLLED tap loop so all buffer indices are
// compile-time (rule #20: runtime-indexed ext_vector arrays go to scratch).
// Invalid lanes (node >= N) gather the all-zero row N (no per-element cndmask).
__global__ __launch_bounds__(64, 4) void conv_k(const unsigned short* __restrict__ xTb,
                                                const int* __restrict__ neigh,
                                                const unsigned short* __restrict__ wTb,
                                                float* __restrict__ y,    // [32][N]
                                                float* __restrict__ tot,  // [32][64] striped
                                                int N) {
    __shared__ float ct[16][33];

    const int L    = threadIdx.x;      // 0..63
    const int r16  = L & 15;
    const int quad = L >> 4;           // 0..3
    const int base = blockIdx.x * 16;
    const int n0   = base + r16;
    const bool v0  = (n0 < N);
    const long nb0 = (long)(v0 ? n0 : 0) * KK;

    f32x4 acc0 = {0.f, 0.f, 0.f, 0.f};
    f32x4 acc1 = acc0;

    bf16x8 A[3], B0[3], B1[3];
    int ja[3];

#pragma unroll
    for (int d = 0; d < 3; ++d) ja[d] = v0 ? neigh[nb0 + d] : N;
#pragma unroll
    for (int d = 0; d < 3; ++d) {
        A[d]  = *(const bf16x8*)(xTb + (long)ja[d] * 32 + quad * 8);
        const unsigned short* wn = wTb + d * 1024;
        B0[d] = *(const bf16x8*)(wn + r16 * 32 + quad * 8);
        B1[d] = *(const bf16x8*)(wn + (16 + r16) * 32 + quad * 8);
        ja[d] = v0 ? neigh[nb0 + d + 3] : N;    // index for tap d+3
    }

#pragma unroll
    for (int t = 0; t < KK; ++t) {
        const int cur = t % 3;   // compile-time: loop is fully unrolled
        acc0 = __builtin_amdgcn_mfma_f32_16x16x32_bf16(A[cur], B0[cur], acc0, 0, 0, 0);
        acc1 = __builtin_amdgcn_mfma_f32_16x16x32_bf16(A[cur], B1[cur], acc1, 0, 0, 0);
        if (t + 3 < KK) {
            A[cur]  = *(const bf16x8*)(xTb + (long)ja[cur] * 32 + quad * 8);
            const unsigned short* wn = wTb + (t + 3) * 1024;
            B0[cur] = *(const bf16x8*)(wn + r16 * 32 + quad * 8);
            B1[cur] = *(const bf16x8*)(wn + (16 + r16) * 32 + quad * 8);
            if (t + 6 < KK) ja[cur] = v0 ? neigh[nb0 + t + 6] : N;
        }
    }

    // BN partials: sum over this wave's 16 nodes.
    // C/D layout: cout = r16 (acc0) / 16+r16 (acc1), node = quad*4 + reg.
    float s0 = 0.f, q0 = 0.f, s1 = 0.f, q1 = 0.f;
#pragma unroll
    for (int r = 0; r < 4; ++r) {
        s0 += acc0[r];
        q0 += acc0[r] * acc0[r];
        s1 += acc1[r];
        q1 += acc1[r] * acc1[r];
    }
#pragma unroll
    for (int off = 16; off < 64; off <<= 1) {   // reduce across quads (nodes)
        s0 += __shfl_xor(s0, off, 64);
        q0 += __shfl_xor(q0, off, 64);
        s1 += __shfl_xor(s1, off, 64);
        q1 += __shfl_xor(q1, off, 64);
    }
    const int stripe = blockIdx.x & 31;         // 32-way striping kills contention
    if (L < 16) {
        float* tb = tot + stripe * 64;
        atomicAdd(&tb[L],      s0);
        atomicAdd(&tb[L + 16], s1);
        atomicAdd(&tb[L + 32], q0);
        atomicAdd(&tb[L + 48], q1);
    }

    // LDS transpose -> coalesced y stores ([cout][node], 16 contiguous nodes/row)
#pragma unroll
    for (int r = 0; r < 4; ++r) {
        ct[quad * 4 + r][r16]      = acc0[r];
        ct[quad * 4 + r][16 + r16] = acc1[r];
    }
    __syncthreads();   // single wave: cheap
    const int node = L & 15;
    const int ch   = L >> 4;                    // 0..3 -> couts ch*8..ch*8+7
    const int gn   = base + node;
    if (gn < N) {
#pragma unroll
        for (int i = 0; i < 8; ++i) {
            const int cout = ch * 8 + i;
            y[(long)cout * N + gn] = ct[node][cout];
        }
    }
}

// ---- Kernel 3: normalize y in place (stripe-reduce + stats finalize fused) ----
__global__ __launch_bounds__(256) void norm_k(float* __restrict__ y,
                                              const float* __restrict__ tot,
                                              const float* __restrict__ gamma,
                                              const float* __restrict__ beta, int N) {
    const int d = blockIdx.y;
    float sm = 0.f, sq = 0.f;
#pragma unroll
    for (int s = 0; s < 32; ++s) {              // reduce the 32 stripes (L2-hot, 8KB)
        sm += tot[s * 64 + d];
        sq += tot[s * 64 + 32 + d];
    }
    const float mean = sm / (float)N;
    const float var  = sq / (float)N - mean * mean;
    const float sc   = gamma[d] * rsqrtf(var + 1e-3f);
    const float sh   = beta[d] - mean * sc;

    int i = blockIdx.x * blockDim.x + threadIdx.x;
    int base = i * 4;
    if (base + 3 < N) {
        float4* p = (float4*)(y + (long)d * N + base);
        float4 v = *p;
        v.x = fmaf(v.x, sc, sh);
        v.y = fmaf(v.y, sc, sh);
        v.z = fmaf(v.z, sc, sh);
        v.w = fmaf(v.w, sc, sh);
        *p = v;
    } else if (base < N) {
        for (int t = base; t < N; ++t) y[(long)d * N + t] = fmaf(y[(long)d * N + t], sc, sh);
    }
}

// ---- launcher ----
extern "C" void kernel_launch(void* const* d_in, const int* in_sizes, int n_in,
                              void* d_out, int out_size, void* d_ws, size_t ws_size,
                              hipStream_t stream) {
    const float* data_in = (const float*)d_in[0];
    const int*   neigh   = (const int*)d_in[1];
    const float* weight  = (const float*)d_in[2];
    const float* gamma   = (const float*)d_in[3];
    const float* beta    = (const float*)d_in[4];
    float* out = (float*)d_out;

    const int N = in_sizes[1] / KK;
    const int nxblk  = (N + 31) / 32;   // x-prep blocks
    const int nblk16 = (N + 15) / 16;   // 16 nodes per 1-wave conv block

    char* ws = (char*)d_ws;
    unsigned short* xTb = (unsigned short*)ws;                            // (N+1)*32 bf16
    unsigned short* wTb = (unsigned short*)(ws + (size_t)(N + 1) * 64);   // 27*1024 bf16
    float* tot = (float*)(ws + (size_t)(N + 1) * 64 + 55296);             // 32*64 floats

    prep_k<<<nxblk + KK, 256, 0, stream>>>(data_in, weight, xTb, wTb, tot, N, nxblk);
    conv_k<<<nblk16, 64, 0, stream>>>(xTb, neigh, wTb, out, tot, N);
    dim3 ngrid(((N + 3) / 4 + 255) / 256, 32);
    norm_k<<<ngrid, 256, 0, stream>>>(out, tot, gamma, beta, N);
}